// Round 8
// baseline (138.360 us; speedup 1.0000x reference)
//
#include <hip/hip_runtime.h>
#include <hip/hip_bf16.h>

#define DH 32
#define BSZ 128      // nodes per bucket (v_local = 7 bits)
#define NBP 1024     // padded bucket count (N <= 131072 => B <= 1024)
#define SCAT_E 2048  // edges per scatter/precount block
#define SCAT_P (2 * SCAT_E)
#define EPT 8        // edges per thread in bucket_scatter
#define CPG 16       // channels per sub-block in bucket_max
#define NSPLIT 2     // 32 / CPG sub-blocks per bucket
#define TS 2048      // pair codes per LDS tile in bucket_max
#define PAD 17       // aggL words per node (16 channels + 1 pad)

// ---------------------------------------------------------------------------
__global__ __launch_bounds__(256) void zero_counts(int* __restrict__ gtotal) {
    int i = blockIdx.x * 256 + threadIdx.x;
    if (i < NBP) gtotal[i] = 0;
}

// ---------------------------------------------------------------------------
// Per-bucket endpoint histogram.
// ---------------------------------------------------------------------------
__global__ __launch_bounds__(256) void precount(
    const int* __restrict__ src, const int* __restrict__ dst,
    int* __restrict__ gtotal, int E)
{
    __shared__ int hist[NBP];
    const int tid = threadIdx.x;
    for (int i = tid; i < NBP; i += 256) hist[i] = 0;
    __syncthreads();
    const int e0 = blockIdx.x * SCAT_E;
    const int eend = min(e0 + SCAT_E, E);
    for (int e = e0 + tid; e < eend; e += 256) {
        atomicAdd(&hist[src[e] >> 7], 1);
        atomicAdd(&hist[dst[e] >> 7], 1);
    }
    __syncthreads();
    for (int i = tid; i < NBP; i += 256)
        if (hist[i] > 0) atomicAdd(&gtotal[i], hist[i]);
}

// ---------------------------------------------------------------------------
// Exclusive scan of gtotal[0..NBP) -> gbase; gcursor = gbase. One block,
// 4 elements per thread.
// ---------------------------------------------------------------------------
__global__ __launch_bounds__(256) void scan_buckets(
    const int* __restrict__ gtotal, int* __restrict__ gbase,
    int* __restrict__ gcursor)
{
    __shared__ int ss[256];
    const int t = threadIdx.x;
    int v0 = gtotal[4 * t], v1 = gtotal[4 * t + 1];
    int v2 = gtotal[4 * t + 2], v3 = gtotal[4 * t + 3];
    int tsum = v0 + v1 + v2 + v3;
    ss[t] = tsum;
    __syncthreads();
    for (int off = 1; off < 256; off <<= 1) {
        int y = (t >= off) ? ss[t - off] : 0;
        __syncthreads();
        ss[t] += y;
        __syncthreads();
    }
    int e = ss[t] - tsum;
    gbase[4 * t] = e;                    gcursor[4 * t] = e;
    gbase[4 * t + 1] = e + v0;           gcursor[4 * t + 1] = e + v0;
    gbase[4 * t + 2] = e + v0 + v1;      gcursor[4 * t + 2] = e + v0 + v1;
    gbase[4 * t + 3] = e + v0 + v1 + v2; gcursor[4 * t + 3] = e + v0 + v1 + v2;
}

// ---------------------------------------------------------------------------
// Bucket-granular scatter: block-local sort by bucket in LDS, then coalesced
// run writes with one global cursor atomic per (block,bucket).
// pair code: (v & 127) << 17 | nbr   (requires N <= 131072)
// ---------------------------------------------------------------------------
__global__ __launch_bounds__(256) void bucket_scatter(
    const int* __restrict__ src, const int* __restrict__ dst,
    int* __restrict__ gcursor, unsigned* __restrict__ pairs_g,
    int E, int B)
{
    __shared__ unsigned s_code[SCAT_P];        // 16 KB
    __shared__ unsigned short s_bkt[SCAT_P];   // 8 KB
    __shared__ int hist[NBP], lbase[NBP], cur[NBP], gbL[NBP];  // 16 KB
    __shared__ int ss[256];

    const int tid = threadIdx.x;
    const int e0 = blockIdx.x * SCAT_E;
    const int eend = min(e0 + SCAT_E, E);
    const int np = 2 * (eend - e0);

    for (int i = tid; i < NBP; i += 256) hist[i] = 0;
    __syncthreads();

    // load up to EPT edges/thread into regs (static indexing only)
    int es[EPT], dr[EPT];
#pragma unroll
    for (int j = 0; j < EPT; ++j) {
        int e = e0 + tid + j * 256;
        bool ok = (e < eend);
        es[j] = ok ? src[e] : -1;
        dr[j] = ok ? dst[e] : -1;
    }
#pragma unroll
    for (int j = 0; j < EPT; ++j) {
        if (es[j] >= 0) {
            atomicAdd(&hist[es[j] >> 7], 1);
            atomicAdd(&hist[dr[j] >> 7], 1);
        }
    }
    __syncthreads();

    // exclusive scan over NBP=1024 (4 elements per thread)
    {
        int v0 = hist[4 * tid], v1 = hist[4 * tid + 1];
        int v2 = hist[4 * tid + 2], v3 = hist[4 * tid + 3];
        int tsum = v0 + v1 + v2 + v3;
        ss[tid] = tsum;
        __syncthreads();
        for (int off = 1; off < 256; off <<= 1) {
            int y = (tid >= off) ? ss[tid - off] : 0;
            __syncthreads();
            ss[tid] += y;
            __syncthreads();
        }
        int e = ss[tid] - tsum;
        lbase[4 * tid] = e;                    cur[4 * tid] = e;
        lbase[4 * tid + 1] = e + v0;           cur[4 * tid + 1] = e + v0;
        lbase[4 * tid + 2] = e + v0 + v1;      cur[4 * tid + 2] = e + v0 + v1;
        lbase[4 * tid + 3] = e + v0 + v1 + v2; cur[4 * tid + 3] = e + v0 + v1 + v2;
    }
    __syncthreads();

    // rank + reorder into LDS
#pragma unroll
    for (int j = 0; j < EPT; ++j) {
        if (es[j] >= 0) {
            int s = es[j], d = dr[j];
            int bs = s >> 7, bd = d >> 7;
            unsigned cs = ((unsigned)(s & 127) << 17) | (unsigned)d;
            unsigned cd = ((unsigned)(d & 127) << 17) | (unsigned)s;
            int p1 = atomicAdd(&cur[bs], 1);
            s_code[p1] = cs; s_bkt[p1] = (unsigned short)bs;
            int p2 = atomicAdd(&cur[bd], 1);
            s_code[p2] = cd; s_bkt[p2] = (unsigned short)bd;
        }
    }
    __syncthreads();

    // allocate global run per bucket
    for (int b = tid; b < B; b += 256) {
        int c = hist[b];
        if (c > 0) {
            int gw = atomicAdd(&gcursor[b], c);
            gbL[b] = gw - lbase[b];
        }
    }
    __syncthreads();

    // coalesced run writes
    for (int i = tid; i < np; i += 256) {
        int b = s_bkt[i];
        pairs_g[gbL[b] + i] = s_code[i];
    }
}

// ---------------------------------------------------------------------------
// One THREAD per node. Weights staged in LDS and read at wave-uniform
// addresses (broadcast, conflict-free); feat row / h / u live in registers.
//   h = feat @ W_in + b_in                  (128 -> 32)
//   u = sigmoid(h @ W_nbr + b_nbr + b_n1)   (32 -> 32), bf16 channel-split
// ---------------------------------------------------------------------------
__global__ __launch_bounds__(128) void node_proj(
    const float* __restrict__ feat,
    const float* __restrict__ W_in, const float* __restrict__ b_in,
    const float* __restrict__ W_nbr, const float* __restrict__ b_nbr,
    const float* __restrict__ b_n1,
    float* __restrict__ h, unsigned short* __restrict__ ub, int N)
{
    __shared__ float sW1[128 * 32];   // [k][c] natural layout, 16 KB
    __shared__ float sW2[32 * 32];    // [k][c], 4 KB
    __shared__ float sb1[32], sb2[32];

    const int tid = threadIdx.x;
    for (int i = tid; i < 128 * 32; i += 128) sW1[i] = W_in[i];
    for (int i = tid; i < 32 * 32; i += 128) sW2[i] = W_nbr[i];
    if (tid < 32) { sb1[tid] = b_in[tid]; sb2[tid] = b_nbr[tid] + b_n1[tid]; }
    __syncthreads();

    const int node = blockIdx.x * 128 + tid;
    if (node >= N) return;

    const float4* frow = (const float4*)(feat + (size_t)node * 128);

    float acc[32];
#pragma unroll
    for (int c = 0; c < 32; ++c) acc[c] = sb1[c];

#pragma unroll 4
    for (int k4 = 0; k4 < 32; ++k4) {
        const float4 f = frow[k4];
        const float4* w0 = (const float4*)&sW1[(k4 * 4 + 0) * 32];
        const float4* w1 = (const float4*)&sW1[(k4 * 4 + 1) * 32];
        const float4* w2 = (const float4*)&sW1[(k4 * 4 + 2) * 32];
        const float4* w3 = (const float4*)&sW1[(k4 * 4 + 3) * 32];
#pragma unroll
        for (int c4 = 0; c4 < 8; ++c4) {
            float4 a0 = w0[c4], a1 = w1[c4], a2 = w2[c4], a3 = w3[c4];
            acc[c4 * 4 + 0] = fmaf(f.w, a3.x, fmaf(f.z, a2.x, fmaf(f.y, a1.x, fmaf(f.x, a0.x, acc[c4 * 4 + 0]))));
            acc[c4 * 4 + 1] = fmaf(f.w, a3.y, fmaf(f.z, a2.y, fmaf(f.y, a1.y, fmaf(f.x, a0.y, acc[c4 * 4 + 1]))));
            acc[c4 * 4 + 2] = fmaf(f.w, a3.z, fmaf(f.z, a2.z, fmaf(f.y, a1.z, fmaf(f.x, a0.z, acc[c4 * 4 + 2]))));
            acc[c4 * 4 + 3] = fmaf(f.w, a3.w, fmaf(f.z, a2.w, fmaf(f.y, a1.w, fmaf(f.x, a0.w, acc[c4 * 4 + 3]))));
        }
    }

    {
        float4* hrow = (float4*)(h + (size_t)node * 32);
#pragma unroll
        for (int c4 = 0; c4 < 8; ++c4)
            hrow[c4] = make_float4(acc[c4 * 4 + 0], acc[c4 * 4 + 1],
                                   acc[c4 * 4 + 2], acc[c4 * 4 + 3]);
    }

    float acc2[32];
#pragma unroll
    for (int c = 0; c < 32; ++c) acc2[c] = sb2[c];
#pragma unroll
    for (int k = 0; k < 32; ++k) {
        const float hv = acc[k];
        const float4* wr = (const float4*)&sW2[k * 32];
#pragma unroll
        for (int c4 = 0; c4 < 8; ++c4) {
            float4 w = wr[c4];
            acc2[c4 * 4 + 0] = fmaf(hv, w.x, acc2[c4 * 4 + 0]);
            acc2[c4 * 4 + 1] = fmaf(hv, w.y, acc2[c4 * 4 + 1]);
            acc2[c4 * 4 + 2] = fmaf(hv, w.z, acc2[c4 * 4 + 2]);
            acc2[c4 * 4 + 3] = fmaf(hv, w.w, acc2[c4 * 4 + 3]);
        }
    }

    // sigmoid -> bf16 (RNE) -> channel-split tables, packed uint writes
    unsigned* ub32 = (unsigned*)ub;
#pragma unroll
    for (int j = 0; j < 16; ++j) {
        const int q = j >> 3, jj = j & 7;
        const int c = q * 16 + 2 * jj;
        float s0 = 1.0f / (1.0f + __expf(-acc2[c]));
        float s1 = 1.0f / (1.0f + __expf(-acc2[c + 1]));
        unsigned b0 = __float_as_uint(s0);
        b0 += 0x7FFFu + ((b0 >> 16) & 1u);
        unsigned b1 = __float_as_uint(s1);
        b1 += 0x7FFFu + ((b1 >> 16) & 1u);
        ub32[((size_t)q * N + node) * 8 + jj] = (b0 >> 16) | (b1 & 0xFFFF0000u);
    }
}

// ---------------------------------------------------------------------------
// Per-bucket segment max in LDS, split 2 ways by channel half (q=blockIdx.y).
// Pair codes staged in LDS tiles (coalesced); 8-lane groups, each lane
// gathers a u32 (2 bf16 channels); 8 pairs in flight per lane.
// aggL stride = PAD(17) words: bank = (17*vl + 2*cl) % 32 mixes parity
// across groups -> ~2-way conflicts instead of structural 4-way.
// ---------------------------------------------------------------------------
__global__ __launch_bounds__(256) void bucket_max(
    const unsigned* __restrict__ pairs_g, const int* __restrict__ gbase,
    const int* __restrict__ gtotal, const unsigned* __restrict__ ub32,
    float* __restrict__ agg, int N)
{
    __shared__ unsigned aggL[BSZ * PAD];   // 8.7 KB
    __shared__ int degL[BSZ];              // 0.5 KB
    __shared__ unsigned tile[TS];          // 8 KB

    const int tid = threadIdx.x;
    const int b = blockIdx.x;
    const int q = blockIdx.y;              // channel half
    const int v0 = b * BSZ;
    const unsigned* ut = ub32 + (size_t)q * N * 8;  // 8 u32 per node

    for (int i = tid; i < BSZ * PAD; i += 256) aggL[i] = 0u;
    for (int i = tid; i < BSZ; i += 256) degL[i] = 0;
    __syncthreads();

    const int start = gbase[b];
    const int cnt = gtotal[b];
    const int gg = tid >> 3;       // 32 groups of 8 lanes
    const int cl = tid & 7;

    for (int t0 = 0; t0 < cnt; t0 += TS) {
        const int tn = min(TS, cnt - t0);
        for (int i = tid; i < tn; i += 256) tile[i] = pairs_g[start + t0 + i];
        __syncthreads();

        const int kmax = (tn - gg + 31) >> 5;   // <=0 if gg >= tn
        for (int kk = 0; kk < kmax; kk += 8) {
            const int pb = (kk << 5) + gg;
            const int pm = tn - 1;
            unsigned c0 = tile[min(pb + 0 * 32, pm)];
            unsigned c1 = tile[min(pb + 1 * 32, pm)];
            unsigned c2 = tile[min(pb + 2 * 32, pm)];
            unsigned c3 = tile[min(pb + 3 * 32, pm)];
            unsigned c4 = tile[min(pb + 4 * 32, pm)];
            unsigned c5 = tile[min(pb + 5 * 32, pm)];
            unsigned c6 = tile[min(pb + 6 * 32, pm)];
            unsigned c7 = tile[min(pb + 7 * 32, pm)];
            unsigned x0 = ut[(size_t)(c0 & 0x1FFFF) * 8 + cl];
            unsigned x1 = ut[(size_t)(c1 & 0x1FFFF) * 8 + cl];
            unsigned x2 = ut[(size_t)(c2 & 0x1FFFF) * 8 + cl];
            unsigned x3 = ut[(size_t)(c3 & 0x1FFFF) * 8 + cl];
            unsigned x4 = ut[(size_t)(c4 & 0x1FFFF) * 8 + cl];
            unsigned x5 = ut[(size_t)(c5 & 0x1FFFF) * 8 + cl];
            unsigned x6 = ut[(size_t)(c6 & 0x1FFFF) * 8 + cl];
            unsigned x7 = ut[(size_t)(c7 & 0x1FFFF) * 8 + cl];
            // duplicate (clamped) pairs are idempotent under max
            atomicMax(&aggL[(c0 >> 17) * PAD + 2 * cl], (x0 & 0xFFFFu) << 16);
            atomicMax(&aggL[(c0 >> 17) * PAD + 2 * cl + 1], x0 & 0xFFFF0000u);
            atomicMax(&aggL[(c1 >> 17) * PAD + 2 * cl], (x1 & 0xFFFFu) << 16);
            atomicMax(&aggL[(c1 >> 17) * PAD + 2 * cl + 1], x1 & 0xFFFF0000u);
            atomicMax(&aggL[(c2 >> 17) * PAD + 2 * cl], (x2 & 0xFFFFu) << 16);
            atomicMax(&aggL[(c2 >> 17) * PAD + 2 * cl + 1], x2 & 0xFFFF0000u);
            atomicMax(&aggL[(c3 >> 17) * PAD + 2 * cl], (x3 & 0xFFFFu) << 16);
            atomicMax(&aggL[(c3 >> 17) * PAD + 2 * cl + 1], x3 & 0xFFFF0000u);
            atomicMax(&aggL[(c4 >> 17) * PAD + 2 * cl], (x4 & 0xFFFFu) << 16);
            atomicMax(&aggL[(c4 >> 17) * PAD + 2 * cl + 1], x4 & 0xFFFF0000u);
            atomicMax(&aggL[(c5 >> 17) * PAD + 2 * cl], (x5 & 0xFFFFu) << 16);
            atomicMax(&aggL[(c5 >> 17) * PAD + 2 * cl + 1], x5 & 0xFFFF0000u);
            atomicMax(&aggL[(c6 >> 17) * PAD + 2 * cl], (x6 & 0xFFFFu) << 16);
            atomicMax(&aggL[(c6 >> 17) * PAD + 2 * cl + 1], x6 & 0xFFFF0000u);
            atomicMax(&aggL[(c7 >> 17) * PAD + 2 * cl], (x7 & 0xFFFFu) << 16);
            atomicMax(&aggL[(c7 >> 17) * PAD + 2 * cl + 1], x7 & 0xFFFF0000u);
            if (cl == 0) {
                if (pb + 0 * 32 < tn) atomicAdd(&degL[c0 >> 17], 1);
                if (pb + 1 * 32 < tn) atomicAdd(&degL[c1 >> 17], 1);
                if (pb + 2 * 32 < tn) atomicAdd(&degL[c2 >> 17], 1);
                if (pb + 3 * 32 < tn) atomicAdd(&degL[c3 >> 17], 1);
                if (pb + 4 * 32 < tn) atomicAdd(&degL[c4 >> 17], 1);
                if (pb + 5 * 32 < tn) atomicAdd(&degL[c5 >> 17], 1);
                if (pb + 6 * 32 < tn) atomicAdd(&degL[c6 >> 17], 1);
                if (pb + 7 * 32 < tn) atomicAdd(&degL[c7 >> 17], 1);
            }
        }
        __syncthreads();
    }

    for (int i = tid; i < BSZ * CPG; i += 256) {
        int vl = i >> 4;
        int v = v0 + vl;
        if (v < N) {
            float val = (degL[vl] > 1) ? __uint_as_float(aggL[vl * PAD + (i & 15)]) : 0.f;
            agg[(size_t)v * DH + q * CPG + (i & 15)] = val;
        }
    }
}

// ---------------------------------------------------------------------------
// One THREAD per node: out = concat(h, agg) @ W_ffnn + b_ffnn.
// ---------------------------------------------------------------------------
__global__ __launch_bounds__(128) void finalize(
    const float* __restrict__ h, const float* __restrict__ agg,
    const float* __restrict__ W_ffnn, const float* __restrict__ b_ffnn,
    float* __restrict__ out, int N)
{
    __shared__ float sW[64 * 32];   // [k][c] natural layout, 8 KB
    __shared__ float sb[32];

    const int tid = threadIdx.x;
    for (int i = tid; i < 64 * 32; i += 128) sW[i] = W_ffnn[i];
    if (tid < 32) sb[tid] = b_ffnn[tid];
    __syncthreads();

    const int node = blockIdx.x * 128 + tid;
    if (node >= N) return;

    const float4* hrow = (const float4*)(h + (size_t)node * 32);
    const float4* arow = (const float4*)(agg + (size_t)node * 32);

    float acc[32];
#pragma unroll
    for (int c = 0; c < 32; ++c) acc[c] = sb[c];

#pragma unroll 2
    for (int k4 = 0; k4 < 8; ++k4) {
        const float4 f = hrow[k4];
        const float4* w0 = (const float4*)&sW[(k4 * 4 + 0) * 32];
        const float4* w1 = (const float4*)&sW[(k4 * 4 + 1) * 32];
        const float4* w2 = (const float4*)&sW[(k4 * 4 + 2) * 32];
        const float4* w3 = (const float4*)&sW[(k4 * 4 + 3) * 32];
#pragma unroll
        for (int c4 = 0; c4 < 8; ++c4) {
            float4 a0 = w0[c4], a1 = w1[c4], a2 = w2[c4], a3 = w3[c4];
            acc[c4 * 4 + 0] = fmaf(f.w, a3.x, fmaf(f.z, a2.x, fmaf(f.y, a1.x, fmaf(f.x, a0.x, acc[c4 * 4 + 0]))));
            acc[c4 * 4 + 1] = fmaf(f.w, a3.y, fmaf(f.z, a2.y, fmaf(f.y, a1.y, fmaf(f.x, a0.y, acc[c4 * 4 + 1]))));
            acc[c4 * 4 + 2] = fmaf(f.w, a3.z, fmaf(f.z, a2.z, fmaf(f.y, a1.z, fmaf(f.x, a0.z, acc[c4 * 4 + 2]))));
            acc[c4 * 4 + 3] = fmaf(f.w, a3.w, fmaf(f.z, a2.w, fmaf(f.y, a1.w, fmaf(f.x, a0.w, acc[c4 * 4 + 3]))));
        }
    }
#pragma unroll 2
    for (int k4 = 0; k4 < 8; ++k4) {
        const float4 f = arow[k4];
        const float4* w0 = (const float4*)&sW[(32 + k4 * 4 + 0) * 32];
        const float4* w1 = (const float4*)&sW[(32 + k4 * 4 + 1) * 32];
        const float4* w2 = (const float4*)&sW[(32 + k4 * 4 + 2) * 32];
        const float4* w3 = (const float4*)&sW[(32 + k4 * 4 + 3) * 32];
#pragma unroll
        for (int c4 = 0; c4 < 8; ++c4) {
            float4 a0 = w0[c4], a1 = w1[c4], a2 = w2[c4], a3 = w3[c4];
            acc[c4 * 4 + 0] = fmaf(f.w, a3.x, fmaf(f.z, a2.x, fmaf(f.y, a1.x, fmaf(f.x, a0.x, acc[c4 * 4 + 0]))));
            acc[c4 * 4 + 1] = fmaf(f.w, a3.y, fmaf(f.z, a2.y, fmaf(f.y, a1.y, fmaf(f.x, a0.y, acc[c4 * 4 + 1]))));
            acc[c4 * 4 + 2] = fmaf(f.w, a3.z, fmaf(f.z, a2.z, fmaf(f.y, a1.z, fmaf(f.x, a0.z, acc[c4 * 4 + 2]))));
            acc[c4 * 4 + 3] = fmaf(f.w, a3.w, fmaf(f.z, a2.w, fmaf(f.y, a1.w, fmaf(f.x, a0.w, acc[c4 * 4 + 3]))));
        }
    }

    float4* orow = (float4*)(out + (size_t)node * 32);
#pragma unroll
    for (int c4 = 0; c4 < 8; ++c4)
        orow[c4] = make_float4(acc[c4 * 4 + 0], acc[c4 * 4 + 1],
                               acc[c4 * 4 + 2], acc[c4 * 4 + 3]);
}

// ---------------------------------------------------------------------------
extern "C" void kernel_launch(void* const* d_in, const int* in_sizes, int n_in,
                              void* d_out, int out_size, void* d_ws, size_t ws_size,
                              hipStream_t stream)
{
    const float* feat   = (const float*)d_in[0];
    const int*   src    = (const int*)d_in[1];
    const int*   dst    = (const int*)d_in[2];
    const float* W_in   = (const float*)d_in[3];
    const float* b_in   = (const float*)d_in[4];
    const float* W_nbr  = (const float*)d_in[5];
    const float* b_nbr  = (const float*)d_in[6];
    const float* b_n1   = (const float*)d_in[7];
    const float* W_ffnn = (const float*)d_in[8];
    const float* b_ffnn = (const float*)d_in[9];
    float* out = (float*)d_out;

    const int N = in_sizes[0] / 128;   // 100000 (N <= 131072 required by packing)
    const int E = in_sizes[1];
    const int B = (N + BSZ - 1) / BSZ; // 782 buckets (<= NBP)

    // u (bf16, channel-split, 6.4MB) aliases d_out (12.8MB): written by
    // node_proj, consumed by bucket_max, then finalize overwrites out.
    unsigned short* ub = (unsigned short*)out;
    float* h       = (float*)d_ws;                  // N*32 f32
    float* agg     = h + (size_t)N * DH;            // N*32 f32
    int*   gtotal  = (int*)(agg + (size_t)N * DH);  // NBP
    int*   gbase   = gtotal + NBP;                  // NBP
    int*   gcursor = gbase + NBP;                   // NBP
    unsigned* pairs_g = (unsigned*)(gcursor + NBP); // 2E u32

    const int egrid = (E + SCAT_E - 1) / SCAT_E;

    zero_counts<<<(NBP + 255) / 256, 256, 0, stream>>>(gtotal);
    precount<<<egrid, 256, 0, stream>>>(src, dst, gtotal, E);
    scan_buckets<<<1, 256, 0, stream>>>(gtotal, gbase, gcursor);
    bucket_scatter<<<egrid, 256, 0, stream>>>(src, dst, gcursor, pairs_g, E, B);
    node_proj<<<(N + 127) / 128, 128, 0, stream>>>(feat, W_in, b_in, W_nbr, b_nbr,
                                                   b_n1, h, ub, N);
    dim3 gmax(B, NSPLIT);
    bucket_max<<<gmax, 256, 0, stream>>>(pairs_g, gbase, gtotal, (const unsigned*)ub,
                                         agg, N);
    finalize<<<(N + 127) / 128, 128, 0, stream>>>(h, agg, W_ffnn, b_ffnn, out, N);
}

// Round 9
// 117.241 us; speedup vs baseline: 1.1801x; 1.1801x over previous
//
#include <hip/hip_runtime.h>
#include <hip/hip_bf16.h>

#define DH 32
#define BSZ 128      // nodes per bucket (v_local = 7 bits)
#define NBP 1024     // padded bucket count (N <= 131072 => B <= 1024)
#define SCAT_E 4096  // edges per scatter/precount block
#define SCAT_P (2 * SCAT_E)
#define EPT 16       // edges per thread in scatter (SCAT_E/256)
#define CPG 16       // channels per sub-block in bucket_max
#define TS 2048      // pair codes per LDS tile in bucket_max
#define PAD 17       // aggL words per node (16 channels + 1 pad)

// ---------------------------------------------------------------------------
__global__ __launch_bounds__(256) void zero_counts(int* __restrict__ gtotal) {
    int i = blockIdx.x * 256 + threadIdx.x;
    if (i < NBP) gtotal[i] = 0;
}

// ---------------------------------------------------------------------------
// Per-bucket endpoint histogram.
// ---------------------------------------------------------------------------
__global__ __launch_bounds__(256) void precount(
    const int* __restrict__ src, const int* __restrict__ dst,
    int* __restrict__ gtotal, int E)
{
    __shared__ int hist[NBP];
    const int tid = threadIdx.x;
    for (int i = tid; i < NBP; i += 256) hist[i] = 0;
    __syncthreads();
    const int e0 = blockIdx.x * SCAT_E;
    const int eend = min(e0 + SCAT_E, E);
    for (int e = e0 + tid; e < eend; e += 256) {
        atomicAdd(&hist[src[e] >> 7], 1);
        atomicAdd(&hist[dst[e] >> 7], 1);
    }
    __syncthreads();
    for (int i = tid; i < NBP; i += 256)
        if (hist[i] > 0) atomicAdd(&gtotal[i], hist[i]);
}

// ---------------------------------------------------------------------------
// Exclusive scan of gtotal[0..NBP) -> gbase; gcursor = gbase. One block.
// ---------------------------------------------------------------------------
__global__ __launch_bounds__(256) void scan_buckets(
    const int* __restrict__ gtotal, int* __restrict__ gbase,
    int* __restrict__ gcursor)
{
    __shared__ int ss[256];
    const int t = threadIdx.x;
    int v0 = gtotal[4 * t], v1 = gtotal[4 * t + 1];
    int v2 = gtotal[4 * t + 2], v3 = gtotal[4 * t + 3];
    int tsum = v0 + v1 + v2 + v3;
    ss[t] = tsum;
    __syncthreads();
    for (int off = 1; off < 256; off <<= 1) {
        int y = (t >= off) ? ss[t - off] : 0;
        __syncthreads();
        ss[t] += y;
        __syncthreads();
    }
    int e = ss[t] - tsum;
    gbase[4 * t] = e;                    gcursor[4 * t] = e;
    gbase[4 * t + 1] = e + v0;           gcursor[4 * t + 1] = e + v0;
    gbase[4 * t + 2] = e + v0 + v1;      gcursor[4 * t + 2] = e + v0 + v1;
    gbase[4 * t + 3] = e + v0 + v1 + v2; gcursor[4 * t + 3] = e + v0 + v1 + v2;
}

// ---------------------------------------------------------------------------
// FUSED kernel: blocks [0, egrid) run the bucket-granular scatter; blocks
// [egrid, egrid+npb) run node_proj (+ the h-half of the FFNN -> hpart).
// The two are independent and both latency-bound; co-residency overlaps them.
// ---------------------------------------------------------------------------
union FusedSmem {
    struct {                                // 61 KB (lbase dropped: = cur-hist)
        unsigned code[SCAT_P];              // 32 KB
        unsigned short bkt[SCAT_P];         // 16 KB
        int hist[NBP], cur[NBP], gbL[NBP];  // 12 KB
        int ss[256];                        // 1 KB
    } sc;
    struct {                                // ~25 KB
        float W1[128 * 32];                 // 16 KB [k][c]
        float W2[32 * 32];                  // 4 KB
        float Wf[32 * 32];                  // 4 KB (W_ffnn rows 0..31)
        float b1[32], b2[32], bf[32];
    } pj;
};

__global__ __launch_bounds__(256) void scatter_proj(
    const int* __restrict__ src, const int* __restrict__ dst,
    int* __restrict__ gcursor, unsigned* __restrict__ pairs_g,
    int E, int B, int egrid,
    const float* __restrict__ feat,
    const float* __restrict__ W_in, const float* __restrict__ b_in,
    const float* __restrict__ W_nbr, const float* __restrict__ b_nbr,
    const float* __restrict__ b_n1,
    const float* __restrict__ W_ffnn, const float* __restrict__ b_ffnn,
    float* __restrict__ hpart, unsigned* __restrict__ ub32, int N)
{
    __shared__ FusedSmem sm;
    const int tid = threadIdx.x;

    if ((int)blockIdx.x < egrid) {
        // ================= scatter path =================
        const int e0 = blockIdx.x * SCAT_E;
        const int eend = min(e0 + SCAT_E, E);
        const int np = 2 * (eend - e0);

        for (int i = tid; i < NBP; i += 256) sm.sc.hist[i] = 0;
        __syncthreads();

        int es[EPT], dr[EPT];
#pragma unroll
        for (int j = 0; j < EPT; ++j) {
            int e = e0 + tid + j * 256;
            bool ok = (e < eend);
            es[j] = ok ? src[e] : -1;
            dr[j] = ok ? dst[e] : -1;
        }
#pragma unroll
        for (int j = 0; j < EPT; ++j) {
            if (es[j] >= 0) {
                atomicAdd(&sm.sc.hist[es[j] >> 7], 1);
                atomicAdd(&sm.sc.hist[dr[j] >> 7], 1);
            }
        }
        __syncthreads();

        // exclusive scan over NBP=1024 (4 elems/thread) -> cur
        {
            int v0 = sm.sc.hist[4 * tid], v1 = sm.sc.hist[4 * tid + 1];
            int v2 = sm.sc.hist[4 * tid + 2], v3 = sm.sc.hist[4 * tid + 3];
            int tsum = v0 + v1 + v2 + v3;
            sm.sc.ss[tid] = tsum;
            __syncthreads();
            for (int off = 1; off < 256; off <<= 1) {
                int y = (tid >= off) ? sm.sc.ss[tid - off] : 0;
                __syncthreads();
                sm.sc.ss[tid] += y;
                __syncthreads();
            }
            int e = sm.sc.ss[tid] - tsum;
            sm.sc.cur[4 * tid] = e;
            sm.sc.cur[4 * tid + 1] = e + v0;
            sm.sc.cur[4 * tid + 2] = e + v0 + v1;
            sm.sc.cur[4 * tid + 3] = e + v0 + v1 + v2;
        }
        __syncthreads();

        // rank + reorder into LDS
#pragma unroll
        for (int j = 0; j < EPT; ++j) {
            if (es[j] >= 0) {
                int s = es[j], d = dr[j];
                int bs = s >> 7, bd = d >> 7;
                unsigned cs = ((unsigned)(s & 127) << 17) | (unsigned)d;
                unsigned cd = ((unsigned)(d & 127) << 17) | (unsigned)s;
                int p1 = atomicAdd(&sm.sc.cur[bs], 1);
                sm.sc.code[p1] = cs; sm.sc.bkt[p1] = (unsigned short)bs;
                int p2 = atomicAdd(&sm.sc.cur[bd], 1);
                sm.sc.code[p2] = cd; sm.sc.bkt[p2] = (unsigned short)bd;
            }
        }
        __syncthreads();

        // allocate global run per bucket (lbase = cur - hist)
        for (int b = tid; b < B; b += 256) {
            int c = sm.sc.hist[b];
            if (c > 0) {
                int gw = atomicAdd(&gcursor[b], c);
                sm.sc.gbL[b] = gw - (sm.sc.cur[b] - c);
            }
        }
        __syncthreads();

        // coalesced run writes
        for (int i = tid; i < np; i += 256) {
            int b = sm.sc.bkt[i];
            pairs_g[sm.sc.gbL[b] + i] = sm.sc.code[i];
        }
    } else {
        // ================= node_proj path =================
        for (int i = tid; i < 128 * 32; i += 256) sm.pj.W1[i] = W_in[i];
        for (int i = tid; i < 32 * 32; i += 256) sm.pj.W2[i] = W_nbr[i];
        for (int i = tid; i < 32 * 32; i += 256) sm.pj.Wf[i] = W_ffnn[i];
        if (tid < 32) {
            sm.pj.b1[tid] = b_in[tid];
            sm.pj.b2[tid] = b_nbr[tid] + b_n1[tid];
            sm.pj.bf[tid] = b_ffnn[tid];
        }
        __syncthreads();

        const int node = ((int)blockIdx.x - egrid) * 256 + tid;
        if (node >= N) return;

        const float4* frow = (const float4*)(feat + (size_t)node * 128);

        float acc[32];
#pragma unroll
        for (int c = 0; c < 32; ++c) acc[c] = sm.pj.b1[c];

        // GEMM1: all lanes broadcast-read the same w row from LDS
#pragma unroll 4
        for (int k4 = 0; k4 < 32; ++k4) {
            const float4 f = frow[k4];
            const float4* w0 = (const float4*)&sm.pj.W1[(k4 * 4 + 0) * 32];
            const float4* w1 = (const float4*)&sm.pj.W1[(k4 * 4 + 1) * 32];
            const float4* w2 = (const float4*)&sm.pj.W1[(k4 * 4 + 2) * 32];
            const float4* w3 = (const float4*)&sm.pj.W1[(k4 * 4 + 3) * 32];
#pragma unroll
            for (int c4 = 0; c4 < 8; ++c4) {
                float4 a0 = w0[c4], a1 = w1[c4], a2 = w2[c4], a3 = w3[c4];
                acc[c4 * 4 + 0] = fmaf(f.w, a3.x, fmaf(f.z, a2.x, fmaf(f.y, a1.x, fmaf(f.x, a0.x, acc[c4 * 4 + 0]))));
                acc[c4 * 4 + 1] = fmaf(f.w, a3.y, fmaf(f.z, a2.y, fmaf(f.y, a1.y, fmaf(f.x, a0.y, acc[c4 * 4 + 1]))));
                acc[c4 * 4 + 2] = fmaf(f.w, a3.z, fmaf(f.z, a2.z, fmaf(f.y, a1.z, fmaf(f.x, a0.z, acc[c4 * 4 + 2]))));
                acc[c4 * 4 + 3] = fmaf(f.w, a3.w, fmaf(f.z, a2.w, fmaf(f.y, a1.w, fmaf(f.x, a0.w, acc[c4 * 4 + 3]))));
            }
        }

        // GEMM2 (u = sigmoid(h @ W2 + b2)) on register-resident h
        {
            float acc2[32];
#pragma unroll
            for (int c = 0; c < 32; ++c) acc2[c] = sm.pj.b2[c];
#pragma unroll
            for (int k = 0; k < 32; ++k) {
                const float hv = acc[k];
                const float4* wr = (const float4*)&sm.pj.W2[k * 32];
#pragma unroll
                for (int c4 = 0; c4 < 8; ++c4) {
                    float4 w = wr[c4];
                    acc2[c4 * 4 + 0] = fmaf(hv, w.x, acc2[c4 * 4 + 0]);
                    acc2[c4 * 4 + 1] = fmaf(hv, w.y, acc2[c4 * 4 + 1]);
                    acc2[c4 * 4 + 2] = fmaf(hv, w.z, acc2[c4 * 4 + 2]);
                    acc2[c4 * 4 + 3] = fmaf(hv, w.w, acc2[c4 * 4 + 3]);
                }
            }
            // sigmoid -> bf16 (RNE) -> channel-split tables, packed u32 writes
#pragma unroll
            for (int j = 0; j < 16; ++j) {
                const int q = j >> 3, jj = j & 7;
                const int c = q * 16 + 2 * jj;
                float s0 = 1.0f / (1.0f + __expf(-acc2[c]));
                float s1 = 1.0f / (1.0f + __expf(-acc2[c + 1]));
                unsigned b0 = __float_as_uint(s0);
                b0 += 0x7FFFu + ((b0 >> 16) & 1u);
                unsigned b1 = __float_as_uint(s1);
                b1 += 0x7FFFu + ((b1 >> 16) & 1u);
                ub32[((size_t)q * N + node) * 8 + jj] = (b0 >> 16) | (b1 & 0xFFFF0000u);
            }
        }

        // hpart = h @ W_ffnn[0:32] + b_ffnn  (h never leaves registers)
        {
            float accf[32];
#pragma unroll
            for (int c = 0; c < 32; ++c) accf[c] = sm.pj.bf[c];
#pragma unroll
            for (int k = 0; k < 32; ++k) {
                const float hv = acc[k];
                const float4* wr = (const float4*)&sm.pj.Wf[k * 32];
#pragma unroll
                for (int c4 = 0; c4 < 8; ++c4) {
                    float4 w = wr[c4];
                    accf[c4 * 4 + 0] = fmaf(hv, w.x, accf[c4 * 4 + 0]);
                    accf[c4 * 4 + 1] = fmaf(hv, w.y, accf[c4 * 4 + 1]);
                    accf[c4 * 4 + 2] = fmaf(hv, w.z, accf[c4 * 4 + 2]);
                    accf[c4 * 4 + 3] = fmaf(hv, w.w, accf[c4 * 4 + 3]);
                }
            }
            float4* hr = (float4*)(hpart + (size_t)node * 32);
#pragma unroll
            for (int c4 = 0; c4 < 8; ++c4)
                hr[c4] = make_float4(accf[c4 * 4 + 0], accf[c4 * 4 + 1],
                                     accf[c4 * 4 + 2], accf[c4 * 4 + 3]);
        }
    }
}

// ---------------------------------------------------------------------------
// Per-bucket segment max in LDS. 1D grid with XCD-aware decode: q (channel
// half) = xcd>=4 so each XCD's L2 caches only ITS 3.2MB u-table.
// ---------------------------------------------------------------------------
__global__ __launch_bounds__(256) void bucket_max(
    const unsigned* __restrict__ pairs_g, const int* __restrict__ gbase,
    const int* __restrict__ gtotal, const unsigned* __restrict__ ub32,
    float* __restrict__ agg, int N, int B)
{
    __shared__ unsigned aggL[BSZ * PAD];   // 8.7 KB
    __shared__ int degL[BSZ];              // 0.5 KB
    __shared__ unsigned tile[TS];          // 8 KB

    const int tid = threadIdx.x;
    const int bid = blockIdx.x;
    const int xcd = bid & 7;
    const int q = xcd >> 2;                          // channel half by XCD group
    const int b = (bid >> 3) * 4 + (xcd & 3);
    if (b >= B) return;
    const int v0 = b * BSZ;
    const unsigned* ut = ub32 + (size_t)q * N * 8;   // 8 u32 per node

    for (int i = tid; i < BSZ * PAD; i += 256) aggL[i] = 0u;
    for (int i = tid; i < BSZ; i += 256) degL[i] = 0;
    __syncthreads();

    const int start = gbase[b];
    const int cnt = gtotal[b];
    const int gg = tid >> 3;       // 32 groups of 8 lanes
    const int cl = tid & 7;

    for (int t0 = 0; t0 < cnt; t0 += TS) {
        const int tn = min(TS, cnt - t0);
        for (int i = tid; i < tn; i += 256) tile[i] = pairs_g[start + t0 + i];
        __syncthreads();

        const int kmax = (tn - gg + 31) >> 5;   // <=0 if gg >= tn
        for (int kk = 0; kk < kmax; kk += 8) {
            const int pb = (kk << 5) + gg;
            const int pm = tn - 1;
            unsigned c0 = tile[min(pb + 0 * 32, pm)];
            unsigned c1 = tile[min(pb + 1 * 32, pm)];
            unsigned c2 = tile[min(pb + 2 * 32, pm)];
            unsigned c3 = tile[min(pb + 3 * 32, pm)];
            unsigned c4 = tile[min(pb + 4 * 32, pm)];
            unsigned c5 = tile[min(pb + 5 * 32, pm)];
            unsigned c6 = tile[min(pb + 6 * 32, pm)];
            unsigned c7 = tile[min(pb + 7 * 32, pm)];
            unsigned x0 = ut[(size_t)(c0 & 0x1FFFF) * 8 + cl];
            unsigned x1 = ut[(size_t)(c1 & 0x1FFFF) * 8 + cl];
            unsigned x2 = ut[(size_t)(c2 & 0x1FFFF) * 8 + cl];
            unsigned x3 = ut[(size_t)(c3 & 0x1FFFF) * 8 + cl];
            unsigned x4 = ut[(size_t)(c4 & 0x1FFFF) * 8 + cl];
            unsigned x5 = ut[(size_t)(c5 & 0x1FFFF) * 8 + cl];
            unsigned x6 = ut[(size_t)(c6 & 0x1FFFF) * 8 + cl];
            unsigned x7 = ut[(size_t)(c7 & 0x1FFFF) * 8 + cl];
            atomicMax(&aggL[(c0 >> 17) * PAD + 2 * cl], (x0 & 0xFFFFu) << 16);
            atomicMax(&aggL[(c0 >> 17) * PAD + 2 * cl + 1], x0 & 0xFFFF0000u);
            atomicMax(&aggL[(c1 >> 17) * PAD + 2 * cl], (x1 & 0xFFFFu) << 16);
            atomicMax(&aggL[(c1 >> 17) * PAD + 2 * cl + 1], x1 & 0xFFFF0000u);
            atomicMax(&aggL[(c2 >> 17) * PAD + 2 * cl], (x2 & 0xFFFFu) << 16);
            atomicMax(&aggL[(c2 >> 17) * PAD + 2 * cl + 1], x2 & 0xFFFF0000u);
            atomicMax(&aggL[(c3 >> 17) * PAD + 2 * cl], (x3 & 0xFFFFu) << 16);
            atomicMax(&aggL[(c3 >> 17) * PAD + 2 * cl + 1], x3 & 0xFFFF0000u);
            atomicMax(&aggL[(c4 >> 17) * PAD + 2 * cl], (x4 & 0xFFFFu) << 16);
            atomicMax(&aggL[(c4 >> 17) * PAD + 2 * cl + 1], x4 & 0xFFFF0000u);
            atomicMax(&aggL[(c5 >> 17) * PAD + 2 * cl], (x5 & 0xFFFFu) << 16);
            atomicMax(&aggL[(c5 >> 17) * PAD + 2 * cl + 1], x5 & 0xFFFF0000u);
            atomicMax(&aggL[(c6 >> 17) * PAD + 2 * cl], (x6 & 0xFFFFu) << 16);
            atomicMax(&aggL[(c6 >> 17) * PAD + 2 * cl + 1], x6 & 0xFFFF0000u);
            atomicMax(&aggL[(c7 >> 17) * PAD + 2 * cl], (x7 & 0xFFFFu) << 16);
            atomicMax(&aggL[(c7 >> 17) * PAD + 2 * cl + 1], x7 & 0xFFFF0000u);
            if (cl == 0) {
                if (pb + 0 * 32 < tn) atomicAdd(&degL[c0 >> 17], 1);
                if (pb + 1 * 32 < tn) atomicAdd(&degL[c1 >> 17], 1);
                if (pb + 2 * 32 < tn) atomicAdd(&degL[c2 >> 17], 1);
                if (pb + 3 * 32 < tn) atomicAdd(&degL[c3 >> 17], 1);
                if (pb + 4 * 32 < tn) atomicAdd(&degL[c4 >> 17], 1);
                if (pb + 5 * 32 < tn) atomicAdd(&degL[c5 >> 17], 1);
                if (pb + 6 * 32 < tn) atomicAdd(&degL[c6 >> 17], 1);
                if (pb + 7 * 32 < tn) atomicAdd(&degL[c7 >> 17], 1);
            }
        }
        __syncthreads();
    }

    for (int i = tid; i < BSZ * CPG; i += 256) {
        int vl = i >> 4;
        int v = v0 + vl;
        if (v < N) {
            float val = (degL[vl] > 1) ? __uint_as_float(aggL[vl * PAD + (i & 15)]) : 0.f;
            agg[(size_t)v * DH + q * CPG + (i & 15)] = val;
        }
    }
}

// ---------------------------------------------------------------------------
// out = hpart + agg @ W_ffnn[32:64]   (one thread per node)
// ---------------------------------------------------------------------------
__global__ __launch_bounds__(256) void fin(
    const float* __restrict__ hpart, const float* __restrict__ agg,
    const float* __restrict__ W_ffnn, float* __restrict__ out, int N)
{
    __shared__ float sW[32 * 32];   // bottom 32 rows, [k][c], 4 KB

    const int tid = threadIdx.x;
    for (int i = tid; i < 32 * 32; i += 256) sW[i] = W_ffnn[1024 + i];
    __syncthreads();

    const int node = blockIdx.x * 256 + tid;
    if (node >= N) return;

    const float4* hr = (const float4*)(hpart + (size_t)node * 32);
    const float4* ar = (const float4*)(agg + (size_t)node * 32);

    float acc[32];
#pragma unroll
    for (int c4 = 0; c4 < 8; ++c4) {
        float4 v = hr[c4];
        acc[c4 * 4 + 0] = v.x; acc[c4 * 4 + 1] = v.y;
        acc[c4 * 4 + 2] = v.z; acc[c4 * 4 + 3] = v.w;
    }

#pragma unroll 2
    for (int k4 = 0; k4 < 8; ++k4) {
        const float4 f = ar[k4];
        const float4* w0 = (const float4*)&sW[(k4 * 4 + 0) * 32];
        const float4* w1 = (const float4*)&sW[(k4 * 4 + 1) * 32];
        const float4* w2 = (const float4*)&sW[(k4 * 4 + 2) * 32];
        const float4* w3 = (const float4*)&sW[(k4 * 4 + 3) * 32];
#pragma unroll
        for (int c4 = 0; c4 < 8; ++c4) {
            float4 a0 = w0[c4], a1 = w1[c4], a2 = w2[c4], a3 = w3[c4];
            acc[c4 * 4 + 0] = fmaf(f.w, a3.x, fmaf(f.z, a2.x, fmaf(f.y, a1.x, fmaf(f.x, a0.x, acc[c4 * 4 + 0]))));
            acc[c4 * 4 + 1] = fmaf(f.w, a3.y, fmaf(f.z, a2.y, fmaf(f.y, a1.y, fmaf(f.x, a0.y, acc[c4 * 4 + 1]))));
            acc[c4 * 4 + 2] = fmaf(f.w, a3.z, fmaf(f.z, a2.z, fmaf(f.y, a1.z, fmaf(f.x, a0.z, acc[c4 * 4 + 2]))));
            acc[c4 * 4 + 3] = fmaf(f.w, a3.w, fmaf(f.z, a2.w, fmaf(f.y, a1.w, fmaf(f.x, a0.w, acc[c4 * 4 + 3]))));
        }
    }

    float4* orow = (float4*)(out + (size_t)node * 32);
#pragma unroll
    for (int c4 = 0; c4 < 8; ++c4)
        orow[c4] = make_float4(acc[c4 * 4 + 0], acc[c4 * 4 + 1],
                               acc[c4 * 4 + 2], acc[c4 * 4 + 3]);
}

// ---------------------------------------------------------------------------
extern "C" void kernel_launch(void* const* d_in, const int* in_sizes, int n_in,
                              void* d_out, int out_size, void* d_ws, size_t ws_size,
                              hipStream_t stream)
{
    const float* feat   = (const float*)d_in[0];
    const int*   src    = (const int*)d_in[1];
    const int*   dst    = (const int*)d_in[2];
    const float* W_in   = (const float*)d_in[3];
    const float* b_in   = (const float*)d_in[4];
    const float* W_nbr  = (const float*)d_in[5];
    const float* b_nbr  = (const float*)d_in[6];
    const float* b_n1   = (const float*)d_in[7];
    const float* W_ffnn = (const float*)d_in[8];
    const float* b_ffnn = (const float*)d_in[9];
    float* out = (float*)d_out;

    const int N = in_sizes[0] / 128;   // 100000 (N <= 131072 required by packing)
    const int E = in_sizes[1];
    const int B = (N + BSZ - 1) / BSZ; // 782 buckets (<= NBP)

    // u (bf16, channel-split, 6.4MB) aliases d_out (12.8MB): written by the
    // proj path, consumed by bucket_max, then fin overwrites out.
    unsigned* ub32 = (unsigned*)out;
    float* hpart   = (float*)d_ws;                    // N*32 f32
    float* agg     = hpart + (size_t)N * DH;          // N*32 f32
    int*   gtotal  = (int*)(agg + (size_t)N * DH);    // NBP
    int*   gbase   = gtotal + NBP;                    // NBP
    int*   gcursor = gbase + NBP;                     // NBP
    unsigned* pairs_g = (unsigned*)(gcursor + NBP);   // 2E u32

    const int egrid = (E + SCAT_E - 1) / SCAT_E;      // 245
    const int npb = (N + 255) / 256;                  // 391

    zero_counts<<<(NBP + 255) / 256, 256, 0, stream>>>(gtotal);
    precount<<<egrid, 256, 0, stream>>>(src, dst, gtotal, E);
    scan_buckets<<<1, 256, 0, stream>>>(gtotal, gbase, gcursor);
    scatter_proj<<<egrid + npb, 256, 0, stream>>>(
        src, dst, gcursor, pairs_g, E, B, egrid,
        feat, W_in, b_in, W_nbr, b_nbr, b_n1, W_ffnn, b_ffnn,
        hpart, ub32, N);
    bucket_max<<<((B + 3) / 4) * 8, 256, 0, stream>>>(
        pairs_g, gbase, gtotal, ub32, agg, N, B);
    fin<<<npb, 256, 0, stream>>>(hpart, agg, W_ffnn, out, N);
}